// Round 5
// baseline (300.631 us; speedup 1.0000x reference)
//
#include <hip/hip_runtime.h>

#define DM    2048
#define NH    16
#define HD    128
#define TSEQ  2048
#define BATCH 2
#define MROWS (BATCH * TSEQ)   // 4096

typedef __bf16 bf16_t;
typedef __bf16 bf16x8 __attribute__((ext_vector_type(8)));
typedef __bf16 bf16x4 __attribute__((ext_vector_type(4)));
typedef float  f32x4  __attribute__((ext_vector_type(4)));
typedef float  f32x16 __attribute__((ext_vector_type(16)));
typedef unsigned short u16x8 __attribute__((ext_vector_type(8)));
typedef unsigned int   u32;

static __device__ __forceinline__ unsigned short f2bf_bits(float f) {
  unsigned u = __builtin_bit_cast(unsigned, f);
  u += 0x7fffu + ((u >> 16) & 1u);            // round-to-nearest-even
  return (unsigned short)(u >> 16);
}
static __device__ __forceinline__ bf16_t f2bf(float f) {
  unsigned short h = f2bf_bits(f);
  return __builtin_bit_cast(bf16_t, h);
}

static __device__ __forceinline__ void gll16(const void* g, void* lds) {
  __builtin_amdgcn_global_load_lds(
      (const __attribute__((address_space(1))) unsigned int*)g,
      (__attribute__((address_space(3))) unsigned int*)lds, 16, 0, 0);
}

static __device__ __forceinline__ float fast_exp2(float x) {
#if __has_builtin(__builtin_amdgcn_exp2f)
  return __builtin_amdgcn_exp2f(x);
#else
  return exp2f(x);
#endif
}
static __device__ __forceinline__ float fast_rcp(float x) {
#if __has_builtin(__builtin_amdgcn_rcpf)
  return __builtin_amdgcn_rcpf(x);
#else
  return 1.0f / x;
#endif
}

// v_cvt_pk_bf16_f32: dst.lo16 = bf16(a), dst.hi16 = bf16(b)
static __device__ __forceinline__ u32 cvtpk(float a, float b) {
  u32 d;
  asm("v_cvt_pk_bf16_f32 %0, %1, %2" : "=v"(d) : "v"(a), "v"(b));
  return d;
}
// v_permlane32_swap_b32 a, b: a.hi32lanes <-> b.lo32lanes
static __device__ __forceinline__ void pl32swap(u32& a, u32& b) {
  asm volatile("v_permlane32_swap_b32 %0, %1" : "+v"(a), "+v"(b));
}

// ---------------- fp32 -> bf16 convert (vectorized, G13) ----------------
__global__ void cvt_bf16(const float* __restrict__ s, bf16_t* __restrict__ d, int n8) {
  int i = blockIdx.x * blockDim.x + threadIdx.x;
  if (i >= n8) return;
  const float4* sp = reinterpret_cast<const float4*>(s);
  float4 a = sp[2 * i], b = sp[2 * i + 1];
  u16x8 o;
  o[0] = f2bf_bits(a.x); o[1] = f2bf_bits(a.y); o[2] = f2bf_bits(a.z); o[3] = f2bf_bits(a.w);
  o[4] = f2bf_bits(b.x); o[5] = f2bf_bits(b.y); o[6] = f2bf_bits(b.z); o[7] = f2bf_bits(b.w);
  reinterpret_cast<u16x8*>(d)[i] = o;
}

// ---------------- 8-phase GEMM: C[M,N] = A[M,K] * B[N,K]^T ----------------
// BM=256, BN=128, BK=64, 512 thr = 8 waves (4M x 2N), per-wave 64x64.
// Double-buffered LDS (96 KB). Per K-tile: 4 phases, each
// {8 swz ds_read_b128 | 1 stage-set | barrier | lgkm0 | prio1 | 8 MFMA | prio0 | barrier}.
// vmcnt(0) only at phase 3 (outstanding == next tile's loads only).
// XOR swizzle: chunk u' = u ^ (row&7) on 128B rows, via pre-swizzled global src.
// OUTM: 0 = fused QKV (bf16; proj 0->Cq rows, 1->Ck rows, 2->Cv as per-head V^T),
//       1 = fp32 row-major to Cq.
template <int OUTM>
__global__ __launch_bounds__(512, 2) void gemm_8ph(
    const bf16_t* __restrict__ A, const bf16_t* __restrict__ B,
    void* __restrict__ Cq, void* __restrict__ Ck, void* __restrict__ Cv) {
  __shared__ bf16_t Asm[2][256 * 64];
  __shared__ bf16_t Bsm[2][128 * 64];
  const int tid = threadIdx.x;
  const int l = tid & 63, w = tid >> 6;
  const int wm = w >> 1, wn = w & 1;
  const int m0 = blockIdx.y * 256, n0 = blockIdx.x * 128;

  auto STAGE_A = [&](int t, int buf, int s) {   // s=0: rows 0..127, s=1: rows 128..255
#pragma unroll
    for (int c = 0; c < 2; ++c) {
      const int rowbase = s * 128 + w * 16 + c * 8;       // wave-uniform
      const int row = rowbase + (l >> 3);
      const int ug = (l & 7) ^ (row & 7);
      gll16(A + (size_t)(m0 + row) * DM + t * 64 + ug * 8,
            (char*)Asm[buf] + rowbase * 128);
    }
  };
  auto STAGE_B = [&](int t, int buf) {          // rows 0..127
#pragma unroll
    for (int c = 0; c < 2; ++c) {
      const int rowbase = w * 16 + c * 8;
      const int row = rowbase + (l >> 3);
      const int ug = (l & 7) ^ (row & 7);
      gll16(B + (size_t)(n0 + row) * DM + t * 64 + ug * 8,
            (char*)Bsm[buf] + rowbase * 128);
    }
  };

  f32x4 acc[4][4] = {};
  const int NT = DM / 64;   // 32

  STAGE_A(0, 0, 0); STAGE_A(0, 0, 1); STAGE_B(0, 0);
  asm volatile("s_waitcnt vmcnt(0)" ::: "memory");
  __syncthreads();
  int cur = 0;

  for (int t = 0; t < NT; ++t) {
    const bool pf = (t + 1 < NT);
#pragma unroll
    for (int ph = 0; ph < 4; ++ph) {
      const int qm = ph >> 1, qn = ph & 1;
      bf16x8 af[2][2], bfm[2][2];
#pragma unroll
      for (int fm = 0; fm < 2; ++fm)
#pragma unroll
        for (int kh = 0; kh < 2; ++kh) {
          const int row = wm * 64 + qm * 32 + fm * 16 + (l & 15);
          const int u = (kh * 4 + (l >> 4)) ^ (row & 7);
          af[fm][kh] = *reinterpret_cast<const bf16x8*>((char*)Asm[cur] + row * 128 + u * 16);
        }
#pragma unroll
      for (int fn = 0; fn < 2; ++fn)
#pragma unroll
        for (int kh = 0; kh < 2; ++kh) {
          const int row = wn * 64 + qn * 32 + fn * 16 + (l & 15);
          const int u = (kh * 4 + (l >> 4)) ^ (row & 7);
          bfm[fn][kh] = *reinterpret_cast<const bf16x8*>((char*)Bsm[cur] + row * 128 + u * 16);
        }
      if (pf) {
        if (ph == 0) STAGE_A(t + 1, cur ^ 1, 0);
        else if (ph == 1) STAGE_A(t + 1, cur ^ 1, 1);
        else if (ph == 2) STAGE_B(t + 1, cur ^ 1);
      }
      __builtin_amdgcn_s_barrier();
      asm volatile("s_waitcnt lgkmcnt(0)" ::: "memory");
      __builtin_amdgcn_sched_barrier(0);
      __builtin_amdgcn_s_setprio(1);
#pragma unroll
      for (int fm = 0; fm < 2; ++fm)
#pragma unroll
        for (int fn = 0; fn < 2; ++fn)
#pragma unroll
          for (int kh = 0; kh < 2; ++kh)
            acc[qm * 2 + fm][qn * 2 + fn] = __builtin_amdgcn_mfma_f32_16x16x32_bf16(
                af[fm][kh], bfm[fn][kh], acc[qm * 2 + fm][qn * 2 + fn], 0, 0, 0);
      __builtin_amdgcn_s_setprio(0);
      if (ph == 3) asm volatile("s_waitcnt vmcnt(0)" ::: "memory");
      __builtin_amdgcn_s_barrier();
    }
    cur ^= 1;
  }

  // ---- epilogue ----
  if constexpr (OUTM == 0) {
    const int proj = n0 >> 11;          // 0=Q, 1=K, 2=V (uniform per WG)
    const int nc0 = n0 & (DM - 1);
    if (proj < 2) {
      bf16_t* C = (bf16_t*)(proj == 0 ? Cq : Ck);
#pragma unroll
      for (int mi = 0; mi < 4; ++mi) {
        const int row = m0 + wm * 64 + mi * 16 + ((l >> 4) << 2);
#pragma unroll
        for (int ni = 0; ni < 4; ++ni) {
          const int col = nc0 + wn * 64 + ni * 16 + (l & 15);
#pragma unroll
          for (int r = 0; r < 4; ++r)
            C[(size_t)(row + r) * DM + col] = f2bf(acc[mi][ni][r]);
        }
      }
    } else {
      bf16_t* VT = (bf16_t*)Cv;
#pragma unroll
      for (int mi = 0; mi < 4; ++mi) {
        const int row = m0 + wm * 64 + mi * 16 + ((l >> 4) << 2);
        const int bb = row >> 11, tt = row & (TSEQ - 1);
#pragma unroll
        for (int ni = 0; ni < 4; ++ni) {
          const int col = nc0 + wn * 64 + ni * 16 + (l & 15);
          const int hh = col >> 7, dd = col & (HD - 1);
          bf16x4 pk;
#pragma unroll
          for (int r = 0; r < 4; ++r) pk[r] = f2bf(acc[mi][ni][r]);
          *reinterpret_cast<bf16x4*>(VT + (((size_t)bb * NH + hh) * HD + dd) * TSEQ + tt) = pk;
        }
      }
    }
  } else {
    float* C = (float*)Cq;
#pragma unroll
    for (int mi = 0; mi < 4; ++mi) {
      const int row = m0 + wm * 64 + mi * 16 + ((l >> 4) << 2);
#pragma unroll
      for (int ni = 0; ni < 4; ++ni) {
        const int col = n0 + wn * 64 + ni * 16 + (l & 15);
#pragma unroll
        for (int r = 0; r < 4; ++r)
          C[(size_t)(row + r) * DM + col] = acc[mi][ni][r];
      }
    }
  }
}

// ---------------- causal flash attention v4: swapped-QK 32x32, in-reg softmax ----
// grid: (T/128, B*H). Block: 256 thr = 4 waves, each wave 32 q-rows.
__global__ __launch_bounds__(256, 2) void flash_attn(
    const bf16_t* __restrict__ Q, const bf16_t* __restrict__ Kx,
    const bf16_t* __restrict__ VT, bf16_t* __restrict__ O) {
  __shared__ bf16_t Ks[2][64 * 128];   // [kv][d], 256B rows, XOR-swizzled content
  __shared__ bf16_t Vs[2][128 * 64];   // [d][kv], 128B rows, XOR-swizzled content
  __shared__ float  Ms[4][32];         // per-wave scl/lrow redistribute buffer

  const int tid = threadIdx.x;
  const int l = tid & 63, w = tid >> 6;
  const int hi = l >> 5, ln31 = l & 31;
  const int qb = (int)gridDim.x - 1 - (int)blockIdx.x;  // long blocks first
  const int bh = blockIdx.y;
  const int b = bh >> 4, h = bh & 15;
  const size_t base   = ((size_t)b * TSEQ) * DM + (size_t)h * HD;   // Q/K/O
  const size_t vtbase = ((size_t)b * NH + h) * HD * (size_t)TSEQ;   // V^T
  const int qbase = qb * 128;
  const int wq0 = qbase + w * 32;
  const int nt = 2 * qb + 2;

  // Q as B-operand: lane holds col q = ln31, k(d) = m*16 + hi*8 + j
  bf16x8 qf[8];
  {
    const bf16_t* qp = Q + base + (size_t)(wq0 + ln31) * DM + hi * 8;
#pragma unroll
    for (int m = 0; m < 8; ++m)
      qf[m] = *reinterpret_cast<const bf16x8*>(qp + m * 16);
  }

  f32x16 acc[4] = {};   // O: row q=crow(r,hi), col d = n*32 + ln31
  float mrow = -1e30f, lrow = 0.f;
  const float cc = 0.12752775f;  // (1/sqrt(128)) * log2(e)

  auto STAGE = [&](int t, int buf) {
#pragma unroll
    for (int c = 0; c < 4; ++c) {
      const int chunk = w * 4 + c;                   // 0..15
      const int krow = chunk * 4 + (l >> 4);
      const int u = l & 15;
      const int ug = (u & 8) | ((u ^ krow) & 7);
      gll16(Kx + base + (size_t)(t * 64 + krow) * DM + ug * 8,
            (char*)Ks[buf] + chunk * 1024);
    }
#pragma unroll
    for (int c = 0; c < 4; ++c) {
      const int ci = w * 4 + c;                      // 0..15
      const int d = ci * 8 + (l >> 3);
      const int ug = (l & 7) ^ (l >> 3);
      gll16(VT + vtbase + (size_t)d * TSEQ + t * 64 + ug * 8,
            (char*)Vs[buf] + ci * 1024);
    }
  };

  STAGE(0, 0);
  __syncthreads();
  int cur = 0;

  for (int t = 0; t < nt; ++t) {
    if (t + 1 < nt) STAGE(t + 1, cur ^ 1);

    const bool active = (t * 64 <= wq0 + 31);
    if (active) {
      // ---- S^T = K Q^T : 2 kv-subtiles of 32 ----
      f32x16 s[2] = {};
      const char* Kb_ = (const char*)Ks[cur];
#pragma unroll
      for (int si = 0; si < 2; ++si) {
        const int kvr = si * 32 + ln31;
#pragma unroll
        for (int m = 0; m < 8; ++m) {
          const int u = 2 * m + hi;
          const int uswz = (u & 8) | ((u ^ kvr) & 7);
          const bf16x8 kf = *reinterpret_cast<const bf16x8*>(Kb_ + kvr * 256 + uswz * 16);
          s[si] = __builtin_amdgcn_mfma_f32_32x32x16_bf16(kf, qf[m], s[si], 0, 0, 0);
        }
      }

      // ---- scale + causal mask (per-lane: q = ln31, kv = crow(r,hi)) ----
      float sv[32];
      const int qg = wq0 + ln31;
#pragma unroll
      for (int si = 0; si < 2; ++si)
#pragma unroll
        for (int r = 0; r < 16; ++r)
          sv[si * 16 + r] = s[si][r] * cc;
      if (t * 64 + 63 > wq0) {
#pragma unroll
        for (int si = 0; si < 2; ++si)
#pragma unroll
          for (int r = 0; r < 16; ++r) {
            const int kvg = t * 64 + si * 32 + (r & 3) + 8 * (r >> 2) + 4 * hi;
            if (kvg > qg) sv[si * 16 + r] = -3.0e38f;
          }
      }

      // ---- in-register row max + cross-half combine ----
      float mt = sv[0];
#pragma unroll
      for (int r = 1; r < 32; ++r) mt = fmaxf(mt, sv[r]);
      mt = fmaxf(mt, __shfl_xor(mt, 32, 64));

      // T13 defer-max
      if (__any(mt > mrow + 8.0f)) {
        const float mn = fmaxf(mrow, mt);
        const float scl = fast_exp2(mrow - mn);
        mrow = mn;
        lrow *= scl;
        if (hi == 0) Ms[w][ln31] = scl;
        float sclg[16];
#pragma unroll
        for (int r = 0; r < 16; ++r)
          sclg[r] = Ms[w][(r & 3) + 8 * (r >> 2) + 4 * hi];
#pragma unroll
        for (int n = 0; n < 4; ++n)
#pragma unroll
          for (int r = 0; r < 16; ++r)
            acc[n][r] *= sclg[r];
      }

      // ---- P = exp2(S - m), row sum ----
      float rs = 0.f;
#pragma unroll
      for (int r = 0; r < 32; ++r) {
        const float p = fast_exp2(sv[r] - mrow);
        sv[r] = p;
        rs += p;
      }
      rs += __shfl_xor(rs, 32, 64);
      lrow += rs;

      // ---- cvt_pk + permlane32_swap: build PV A-frags ----
      u32 frag[4][4];
#pragma unroll
      for (int si = 0; si < 2; ++si) {
#pragma unroll
        for (int half = 0; half < 2; ++half) {
          const float* p = &sv[si * 16 + half * 8];
          u32 a1 = cvtpk(p[0], p[1]);
          u32 b1 = cvtpk(p[4], p[5]);
          pl32swap(a1, b1);
          u32 a2 = cvtpk(p[2], p[3]);
          u32 b2 = cvtpk(p[6], p[7]);
          pl32swap(a2, b2);
          frag[si * 2 + half][0] = a1;
          frag[si * 2 + half][1] = a2;
          frag[si * 2 + half][2] = b1;
          frag[si * 2 + half][3] = b2;
        }
      }

      // ---- O += P V : 4 kv-slots x 4 d-tiles ----
      const char* Vb_ = (const char*)Vs[cur];
#pragma unroll
      for (int ks = 0; ks < 4; ++ks) {
        const bf16x8 pf = __builtin_bit_cast(bf16x8, *reinterpret_cast<u32(*)[4]>(frag[ks]));
#pragma unroll
        for (int n = 0; n < 4; ++n) {
          const int d = n * 32 + ln31;
          const int u = ks * 2 + hi;
          const int uswz = u ^ (d & 7);
          const bf16x8 vf = *reinterpret_cast<const bf16x8*>(Vb_ + d * 128 + uswz * 16);
          acc[n] = __builtin_amdgcn_mfma_f32_32x32x16_bf16(pf, vf, acc[n], 0, 0, 0);
        }
      }
    }
    __syncthreads();
    cur ^= 1;
  }

  // ---- epilogue: redistribute lrow, normalize, store ----
  if (hi == 0) Ms[w][ln31] = lrow;
  __syncthreads();
  float rl[16];
#pragma unroll
  for (int r = 0; r < 16; ++r)
    rl[r] = fast_rcp(Ms[w][(r & 3) + 8 * (r >> 2) + 4 * hi]);
#pragma unroll
  for (int r = 0; r < 16; ++r) {
    const int q = wq0 + (r & 3) + 8 * (r >> 2) + 4 * hi;
    bf16_t* op = O + base + (size_t)q * DM + ln31;
#pragma unroll
    for (int n = 0; n < 4; ++n)
      op[n * 32] = f2bf(acc[n][r] * rl[r]);
  }
}

// ---------------- launch ----------------
extern "C" void kernel_launch(void* const* d_in, const int* in_sizes, int n_in,
                              void* d_out, int out_size, void* d_ws, size_t ws_size,
                              hipStream_t stream) {
  (void)in_sizes; (void)n_in; (void)out_size; (void)ws_size;
  const float* x  = (const float*)d_in[0];
  const float* wq = (const float*)d_in[1];
  const float* wk = (const float*)d_in[2];
  const float* wv = (const float*)d_in[3];
  const float* wo = (const float*)d_in[4];
  float* out = (float*)d_out;

  const size_t nx = (size_t)MROWS * DM;  // 8388608
  const size_t nw = (size_t)DM * DM;     // 4194304
  bf16_t* xb  = (bf16_t*)d_ws;
  bf16_t* wqb = xb + nx;                 // wq/wk/wv contiguous -> fused B [6144][2048]
  bf16_t* wkb = wqb + nw;
  bf16_t* wvb = wkb + nw;
  bf16_t* wob = wvb + nw;
  bf16_t* Qb  = wob + nw;
  bf16_t* Kb  = Qb + nx;
  bf16_t* Vtb = Kb + nx;   // V^T [B][H][d][t]
  bf16_t* Ab  = Vtb + nx;

  cvt_bf16<<<(int)(nx / 8 / 256), 256, 0, stream>>>(x, xb, (int)(nx / 8));
  cvt_bf16<<<(int)(nw / 8 / 256), 256, 0, stream>>>(wq, wqb, (int)(nw / 8));
  cvt_bf16<<<(int)(nw / 8 / 256), 256, 0, stream>>>(wk, wkb, (int)(nw / 8));
  cvt_bf16<<<(int)(nw / 8 / 256), 256, 0, stream>>>(wv, wvb, (int)(nw / 8));
  cvt_bf16<<<(int)(nw / 8 / 256), 256, 0, stream>>>(wo, wob, (int)(nw / 8));

  // fused QKV: B rows 0..2047 -> Q, 2048..4095 -> K, 4096..6143 -> V(T)
  gemm_8ph<0><<<dim3(3 * DM / 128, MROWS / 256), 512, 0, stream>>>(
      xb, wqb, Qb, Kb, Vtb);

  flash_attn<<<dim3(TSEQ / 128, BATCH * NH), 256, 0, stream>>>(Qb, Kb, Vtb, Ab);

  gemm_8ph<1><<<dim3(DM / 128, MROWS / 256), 512, 0, stream>>>(
      Ab, wob, out, nullptr, nullptr);
}

// Round 6
// 251.825 us; speedup vs baseline: 1.1938x; 1.1938x over previous
//
#include <hip/hip_runtime.h>

#define DM    2048
#define NH    16
#define HD    128
#define TSEQ  2048
#define BATCH 2
#define MROWS (BATCH * TSEQ)   // 4096

typedef __bf16 bf16_t;
typedef __bf16 bf16x8 __attribute__((ext_vector_type(8)));
typedef __bf16 bf16x4 __attribute__((ext_vector_type(4)));
typedef float  f32x4  __attribute__((ext_vector_type(4)));
typedef float  f32x16 __attribute__((ext_vector_type(16)));
typedef unsigned short u16x8 __attribute__((ext_vector_type(8)));
typedef unsigned int   u32;

static __device__ __forceinline__ unsigned short f2bf_bits(float f) {
  unsigned u = __builtin_bit_cast(unsigned, f);
  u += 0x7fffu + ((u >> 16) & 1u);            // round-to-nearest-even
  return (unsigned short)(u >> 16);
}
static __device__ __forceinline__ bf16_t f2bf(float f) {
  unsigned short h = f2bf_bits(f);
  return __builtin_bit_cast(bf16_t, h);
}

static __device__ __forceinline__ void gll16(const void* g, void* lds) {
  __builtin_amdgcn_global_load_lds(
      (const __attribute__((address_space(1))) unsigned int*)g,
      (__attribute__((address_space(3))) unsigned int*)lds, 16, 0, 0);
}

static __device__ __forceinline__ float fast_exp2(float x) {
#if __has_builtin(__builtin_amdgcn_exp2f)
  return __builtin_amdgcn_exp2f(x);
#else
  return exp2f(x);
#endif
}
static __device__ __forceinline__ float fast_rcp(float x) {
#if __has_builtin(__builtin_amdgcn_rcpf)
  return __builtin_amdgcn_rcpf(x);
#else
  return 1.0f / x;
#endif
}

// v_cvt_pk_bf16_f32: dst.lo16 = bf16(a), dst.hi16 = bf16(b)
static __device__ __forceinline__ u32 cvtpk(float a, float b) {
  u32 d;
  asm("v_cvt_pk_bf16_f32 %0, %1, %2" : "=v"(d) : "v"(a), "v"(b));
  return d;
}
// v_permlane32_swap_b32 a, b: a.hi32lanes <-> b.lo32lanes
static __device__ __forceinline__ void pl32swap(u32& a, u32& b) {
  asm volatile("v_permlane32_swap_b32 %0, %1" : "+v"(a), "+v"(b));
}

// ---------------- fp32 -> bf16 convert (vectorized, G13) ----------------
__global__ void cvt_bf16(const float* __restrict__ s, bf16_t* __restrict__ d, int n8) {
  int i = blockIdx.x * blockDim.x + threadIdx.x;
  if (i >= n8) return;
  const float4* sp = reinterpret_cast<const float4*>(s);
  float4 a = sp[2 * i], b = sp[2 * i + 1];
  u16x8 o;
  o[0] = f2bf_bits(a.x); o[1] = f2bf_bits(a.y); o[2] = f2bf_bits(a.z); o[3] = f2bf_bits(a.w);
  o[4] = f2bf_bits(b.x); o[5] = f2bf_bits(b.y); o[6] = f2bf_bits(b.z); o[7] = f2bf_bits(b.w);
  reinterpret_cast<u16x8*>(d)[i] = o;
}

// ---------------- 3-buffer counted-vmcnt GEMM: C[M,N] = A[M,K] * B[N,K]^T ------
// BM=256, BN=128, BK=64, 512 thr = 8 waves (4M x 2N), per-wave 64x64.
// 3 LDS buffers (144 KB): compute tile j from buf j%3, stage tile j+2 into
// buf (j+2)%3 (never read/written concurrently -> race-free by construction).
// vmcnt(6) once per K-tile (= tile j+2's 6 loads outstanding); NEVER vmcnt(0)
// in the main loop. Raw s_barrier (no __syncthreads -> no hidden drain).
// XOR swizzle u^=(row&7) on 128B rows via pre-swizzled global src (both sides).
// OUTM: 0 = fused QKV epilogue (Q,K row-major bf16; V as per-head V^T),
//       1 = fp32 row-major to Cq.
template <int OUTM>
__global__ __launch_bounds__(512, 1) void gemm_3buf(
    const bf16_t* __restrict__ A, const bf16_t* __restrict__ B,
    void* __restrict__ Cq, void* __restrict__ Ck, void* __restrict__ Cv) {
  __shared__ bf16_t Asm[3][256 * 64];   // 96 KB
  __shared__ bf16_t Bsm[3][128 * 64];   // 48 KB
  const int tid = threadIdx.x;
  const int l = tid & 63, w = tid >> 6;
  const int wm = w >> 1, wn = w & 1;
  const int m0 = blockIdx.y * 256, n0 = blockIdx.x * 128;
  const int NT = DM / 64;   // 32

  // Stage one 64-row load-set (512 lanes x 16B = 64 rows x 128B).
  auto SA = [&](int t, int buf, int s) {          // s = 0..3 (A: 256 rows)
    const int rowbase = s * 64 + w * 8;           // wave-uniform
    const int row = rowbase + (l >> 3);
    const int ug = (l & 7) ^ (row & 7);
    const int tc = (t < NT) ? t : 0;              // dummy clamp (keeps vmcnt uniform)
    gll16(A + (size_t)(m0 + row) * DM + tc * 64 + ug * 8,
          (char*)Asm[buf] + rowbase * 128);
  };
  auto SB = [&](int t, int buf, int s) {          // s = 0..1 (B: 128 rows)
    const int rowbase = s * 64 + w * 8;
    const int row = rowbase + (l >> 3);
    const int ug = (l & 7) ^ (row & 7);
    const int tc = (t < NT) ? t : 0;
    gll16(B + (size_t)(n0 + row) * DM + tc * 64 + ug * 8,
          (char*)Bsm[buf] + rowbase * 128);
  };

  f32x4 acc[4][4] = {};

  // Prologue: stage tiles 0 and 1 (6 loads each).
#pragma unroll
  for (int s = 0; s < 4; ++s) SA(0, 0, s);
  SB(0, 0, 0); SB(0, 0, 1);
#pragma unroll
  for (int s = 0; s < 4; ++s) SA(1, 1, s);
  SB(1, 1, 0); SB(1, 1, 1);
  asm volatile("s_waitcnt vmcnt(6)" ::: "memory");   // tile 0 complete
  __builtin_amdgcn_s_barrier();
  __builtin_amdgcn_sched_barrier(0);

  for (int j = 0; j < NT; ++j) {
    const int bj = j % 3, bs = (j + 2) % 3;
    const char* Ab_ = (const char*)Asm[bj];
    const char* Bb_ = (const char*)Bsm[bj];
    bf16x8 af[4][2], bfr[4][2];

    // ---- phase A: all A-frags + B-frags ni 0..1; stage A s0..s2 of tile j+2 ----
#pragma unroll
    for (int mi = 0; mi < 4; ++mi)
#pragma unroll
      for (int kh = 0; kh < 2; ++kh) {
        const int row = wm * 64 + mi * 16 + (l & 15);
        const int u = (kh * 4 + (l >> 4)) ^ (row & 7);
        af[mi][kh] = *reinterpret_cast<const bf16x8*>(Ab_ + row * 128 + u * 16);
      }
#pragma unroll
    for (int ni = 0; ni < 2; ++ni)
#pragma unroll
      for (int kh = 0; kh < 2; ++kh) {
        const int row = wn * 64 + ni * 16 + (l & 15);
        const int u = (kh * 4 + (l >> 4)) ^ (row & 7);
        bfr[ni][kh] = *reinterpret_cast<const bf16x8*>(Bb_ + row * 128 + u * 16);
      }
    SA(j + 2, bs, 0); SA(j + 2, bs, 1); SA(j + 2, bs, 2);
    __builtin_amdgcn_s_barrier();
    asm volatile("s_waitcnt lgkmcnt(0)" ::: "memory");
    __builtin_amdgcn_sched_barrier(0);
    __builtin_amdgcn_s_setprio(1);
#pragma unroll
    for (int mi = 0; mi < 4; ++mi)
#pragma unroll
      for (int ni = 0; ni < 2; ++ni)
#pragma unroll
        for (int kh = 0; kh < 2; ++kh)
          acc[mi][ni] = __builtin_amdgcn_mfma_f32_16x16x32_bf16(
              af[mi][kh], bfr[ni][kh], acc[mi][ni], 0, 0, 0);
    __builtin_amdgcn_s_setprio(0);
    __builtin_amdgcn_s_barrier();
    __builtin_amdgcn_sched_barrier(0);

    // ---- phase B: B-frags ni 2..3; stage A s3 + B s0..s1 of tile j+2 ----
#pragma unroll
    for (int ni = 2; ni < 4; ++ni)
#pragma unroll
      for (int kh = 0; kh < 2; ++kh) {
        const int row = wn * 64 + ni * 16 + (l & 15);
        const int u = (kh * 4 + (l >> 4)) ^ (row & 7);
        bfr[ni][kh] = *reinterpret_cast<const bf16x8*>(Bb_ + row * 128 + u * 16);
      }
    SA(j + 2, bs, 3); SB(j + 2, bs, 0); SB(j + 2, bs, 1);
    __builtin_amdgcn_s_barrier();
    asm volatile("s_waitcnt lgkmcnt(0)" ::: "memory");
    __builtin_amdgcn_sched_barrier(0);
    __builtin_amdgcn_s_setprio(1);
#pragma unroll
    for (int mi = 0; mi < 4; ++mi)
#pragma unroll
      for (int ni = 2; ni < 4; ++ni)
#pragma unroll
        for (int kh = 0; kh < 2; ++kh)
          acc[mi][ni] = __builtin_amdgcn_mfma_f32_16x16x32_bf16(
              af[mi][kh], bfr[ni][kh], acc[mi][ni], 0, 0, 0);
    __builtin_amdgcn_s_setprio(0);
    // counted: only tile j+2's 6 loads may remain in flight -> tile j+1 ready
    asm volatile("s_waitcnt vmcnt(6)" ::: "memory");
    __builtin_amdgcn_s_barrier();
    __builtin_amdgcn_sched_barrier(0);
  }

  // ---- epilogue ----
  if constexpr (OUTM == 0) {
    const int proj = n0 >> 11;          // 0=Q, 1=K, 2=V (uniform per WG)
    const int nc0 = n0 & (DM - 1);
    if (proj < 2) {
      bf16_t* C = (bf16_t*)(proj == 0 ? Cq : Ck);
#pragma unroll
      for (int mi = 0; mi < 4; ++mi) {
        const int row = m0 + wm * 64 + mi * 16 + ((l >> 4) << 2);
#pragma unroll
        for (int ni = 0; ni < 4; ++ni) {
          const int col = nc0 + wn * 64 + ni * 16 + (l & 15);
#pragma unroll
          for (int r = 0; r < 4; ++r)
            C[(size_t)(row + r) * DM + col] = f2bf(acc[mi][ni][r]);
        }
      }
    } else {
      bf16_t* VT = (bf16_t*)Cv;
#pragma unroll
      for (int mi = 0; mi < 4; ++mi) {
        const int row = m0 + wm * 64 + mi * 16 + ((l >> 4) << 2);
        const int bb = row >> 11, tt = row & (TSEQ - 1);
#pragma unroll
        for (int ni = 0; ni < 4; ++ni) {
          const int col = nc0 + wn * 64 + ni * 16 + (l & 15);
          const int hh = col >> 7, dd = col & (HD - 1);
          bf16x4 pk;
#pragma unroll
          for (int r = 0; r < 4; ++r) pk[r] = f2bf(acc[mi][ni][r]);
          *reinterpret_cast<bf16x4*>(VT + (((size_t)bb * NH + hh) * HD + dd) * TSEQ + tt) = pk;
        }
      }
    }
  } else {
    float* C = (float*)Cq;
#pragma unroll
    for (int mi = 0; mi < 4; ++mi) {
      const int row = m0 + wm * 64 + mi * 16 + ((l >> 4) << 2);
#pragma unroll
      for (int ni = 0; ni < 4; ++ni) {
        const int col = n0 + wn * 64 + ni * 16 + (l & 15);
#pragma unroll
        for (int r = 0; r < 4; ++r)
          C[(size_t)(row + r) * DM + col] = acc[mi][ni][r];
      }
    }
  }
}

// ---------------- causal flash attention v4: swapped-QK 32x32, in-reg softmax ----
// grid: (T/128, B*H). Block: 256 thr = 4 waves, each wave 32 q-rows.
__global__ __launch_bounds__(256, 2) void flash_attn(
    const bf16_t* __restrict__ Q, const bf16_t* __restrict__ Kx,
    const bf16_t* __restrict__ VT, bf16_t* __restrict__ O) {
  __shared__ bf16_t Ks[2][64 * 128];   // [kv][d], 256B rows, XOR-swizzled content
  __shared__ bf16_t Vs[2][128 * 64];   // [d][kv], 128B rows, XOR-swizzled content
  __shared__ float  Ms[4][32];         // per-wave scl/lrow redistribute buffer

  const int tid = threadIdx.x;
  const int l = tid & 63, w = tid >> 6;
  const int hi = l >> 5, ln31 = l & 31;
  const int qb = (int)gridDim.x - 1 - (int)blockIdx.x;  // long blocks first
  const int bh = blockIdx.y;
  const int b = bh >> 4, h = bh & 15;
  const size_t base   = ((size_t)b * TSEQ) * DM + (size_t)h * HD;   // Q/K/O
  const size_t vtbase = ((size_t)b * NH + h) * HD * (size_t)TSEQ;   // V^T
  const int qbase = qb * 128;
  const int wq0 = qbase + w * 32;
  const int nt = 2 * qb + 2;

  // Q as B-operand: lane holds col q = ln31, k(d) = m*16 + hi*8 + j
  bf16x8 qf[8];
  {
    const bf16_t* qp = Q + base + (size_t)(wq0 + ln31) * DM + hi * 8;
#pragma unroll
    for (int m = 0; m < 8; ++m)
      qf[m] = *reinterpret_cast<const bf16x8*>(qp + m * 16);
  }

  f32x16 acc[4] = {};   // O: row q=crow(r,hi), col d = n*32 + ln31
  float mrow = -1e30f, lrow = 0.f;
  const float cc = 0.12752775f;  // (1/sqrt(128)) * log2(e)

  auto STAGE = [&](int t, int buf) {
#pragma unroll
    for (int c = 0; c < 4; ++c) {
      const int chunk = w * 4 + c;                   // 0..15
      const int krow = chunk * 4 + (l >> 4);
      const int u = l & 15;
      const int ug = (u & 8) | ((u ^ krow) & 7);
      gll16(Kx + base + (size_t)(t * 64 + krow) * DM + ug * 8,
            (char*)Ks[buf] + chunk * 1024);
    }
#pragma unroll
    for (int c = 0; c < 4; ++c) {
      const int ci = w * 4 + c;                      // 0..15
      const int d = ci * 8 + (l >> 3);
      const int ug = (l & 7) ^ (l >> 3);
      gll16(VT + vtbase + (size_t)d * TSEQ + t * 64 + ug * 8,
            (char*)Vs[buf] + ci * 1024);
    }
  };

  STAGE(0, 0);
  __syncthreads();
  int cur = 0;

  for (int t = 0; t < nt; ++t) {
    if (t + 1 < nt) STAGE(t + 1, cur ^ 1);

    const bool active = (t * 64 <= wq0 + 31);
    if (active) {
      // ---- S^T = K Q^T : 2 kv-subtiles of 32 ----
      f32x16 s[2] = {};
      const char* Kb_ = (const char*)Ks[cur];
#pragma unroll
      for (int si = 0; si < 2; ++si) {
        const int kvr = si * 32 + ln31;
#pragma unroll
        for (int m = 0; m < 8; ++m) {
          const int u = 2 * m + hi;
          const int uswz = (u & 8) | ((u ^ kvr) & 7);
          const bf16x8 kf = *reinterpret_cast<const bf16x8*>(Kb_ + kvr * 256 + uswz * 16);
          s[si] = __builtin_amdgcn_mfma_f32_32x32x16_bf16(kf, qf[m], s[si], 0, 0, 0);
        }
      }

      // ---- scale + causal mask (per-lane: q = ln31, kv = crow(r,hi)) ----
      float sv[32];
      const int qg = wq0 + ln31;
#pragma unroll
      for (int si = 0; si < 2; ++si)
#pragma unroll
        for (int r = 0; r < 16; ++r)
          sv[si * 16 + r] = s[si][r] * cc;
      if (t * 64 + 63 > wq0) {
#pragma unroll
        for (int si = 0; si < 2; ++si)
#pragma unroll
          for (int r = 0; r < 16; ++r) {
            const int kvg = t * 64 + si * 32 + (r & 3) + 8 * (r >> 2) + 4 * hi;
            if (kvg > qg) sv[si * 16 + r] = -3.0e38f;
          }
      }

      // ---- in-register row max + cross-half combine ----
      float mt = sv[0];
#pragma unroll
      for (int r = 1; r < 32; ++r) mt = fmaxf(mt, sv[r]);
      mt = fmaxf(mt, __shfl_xor(mt, 32, 64));

      // T13 defer-max
      if (__any(mt > mrow + 8.0f)) {
        const float mn = fmaxf(mrow, mt);
        const float scl = fast_exp2(mrow - mn);
        mrow = mn;
        lrow *= scl;
        if (hi == 0) Ms[w][ln31] = scl;
        float sclg[16];
#pragma unroll
        for (int r = 0; r < 16; ++r)
          sclg[r] = Ms[w][(r & 3) + 8 * (r >> 2) + 4 * hi];
#pragma unroll
        for (int n = 0; n < 4; ++n)
#pragma unroll
          for (int r = 0; r < 16; ++r)
            acc[n][r] *= sclg[r];
      }

      // ---- P = exp2(S - m), row sum ----
      float rs = 0.f;
#pragma unroll
      for (int r = 0; r < 32; ++r) {
        const float p = fast_exp2(sv[r] - mrow);
        sv[r] = p;
        rs += p;
      }
      rs += __shfl_xor(rs, 32, 64);
      lrow += rs;

      // ---- cvt_pk + permlane32_swap: build PV A-frags ----
      u32 frag[4][4];
#pragma unroll
      for (int si = 0; si < 2; ++si) {
#pragma unroll
        for (int half = 0; half < 2; ++half) {
          const float* p = &sv[si * 16 + half * 8];
          u32 a1 = cvtpk(p[0], p[1]);
          u32 b1 = cvtpk(p[4], p[5]);
          pl32swap(a1, b1);
          u32 a2 = cvtpk(p[2], p[3]);
          u32 b2 = cvtpk(p[6], p[7]);
          pl32swap(a2, b2);
          frag[si * 2 + half][0] = a1;
          frag[si * 2 + half][1] = a2;
          frag[si * 2 + half][2] = b1;
          frag[si * 2 + half][3] = b2;
        }
      }

      // ---- O += P V : 4 kv-slots x 4 d-tiles ----
      const char* Vb_ = (const char*)Vs[cur];
#pragma unroll
      for (int ks = 0; ks < 4; ++ks) {
        const bf16x8 pf = __builtin_bit_cast(bf16x8, *reinterpret_cast<u32(*)[4]>(frag[ks]));
#pragma unroll
        for (int n = 0; n < 4; ++n) {
          const int d = n * 32 + ln31;
          const int u = ks * 2 + hi;
          const int uswz = u ^ (d & 7);
          const bf16x8 vf = *reinterpret_cast<const bf16x8*>(Vb_ + d * 128 + uswz * 16);
          acc[n] = __builtin_amdgcn_mfma_f32_32x32x16_bf16(pf, vf, acc[n], 0, 0, 0);
        }
      }
    }
    __syncthreads();
    cur ^= 1;
  }

  // ---- epilogue: redistribute lrow, normalize, store ----
  if (hi == 0) Ms[w][ln31] = lrow;
  __syncthreads();
  float rl[16];
#pragma unroll
  for (int r = 0; r < 16; ++r)
    rl[r] = fast_rcp(Ms[w][(r & 3) + 8 * (r >> 2) + 4 * hi]);
#pragma unroll
  for (int r = 0; r < 16; ++r) {
    const int q = wq0 + (r & 3) + 8 * (r >> 2) + 4 * hi;
    bf16_t* op = O + base + (size_t)q * DM + ln31;
#pragma unroll
    for (int n = 0; n < 4; ++n)
      op[n * 32] = f2bf(acc[n][r] * rl[r]);
  }
}

// ---------------- launch ----------------
extern "C" void kernel_launch(void* const* d_in, const int* in_sizes, int n_in,
                              void* d_out, int out_size, void* d_ws, size_t ws_size,
                              hipStream_t stream) {
  (void)in_sizes; (void)n_in; (void)out_size; (void)ws_size;
  const float* x  = (const float*)d_in[0];
  const float* wq = (const float*)d_in[1];
  const float* wk = (const float*)d_in[2];
  const float* wv = (const float*)d_in[3];
  const float* wo = (const float*)d_in[4];
  float* out = (float*)d_out;

  const size_t nx = (size_t)MROWS * DM;  // 8388608
  const size_t nw = (size_t)DM * DM;     // 4194304
  bf16_t* xb  = (bf16_t*)d_ws;
  bf16_t* wqb = xb + nx;                 // wq/wk/wv contiguous -> fused B [6144][2048]
  bf16_t* wkb = wqb + nw;
  bf16_t* wvb = wkb + nw;
  bf16_t* wob = wvb + nw;
  bf16_t* Qb  = wob + nw;
  bf16_t* Kb  = Qb + nx;
  bf16_t* Vtb = Kb + nx;   // V^T [B][H][d][t]
  bf16_t* Ab  = Vtb + nx;

  cvt_bf16<<<(int)(nx / 8 / 256), 256, 0, stream>>>(x, xb, (int)(nx / 8));
  cvt_bf16<<<(int)(nw / 8 / 256), 256, 0, stream>>>(wq, wqb, (int)(nw / 8));
  cvt_bf16<<<(int)(nw / 8 / 256), 256, 0, stream>>>(wk, wkb, (int)(nw / 8));
  cvt_bf16<<<(int)(nw / 8 / 256), 256, 0, stream>>>(wv, wvb, (int)(nw / 8));
  cvt_bf16<<<(int)(nw / 8 / 256), 256, 0, stream>>>(wo, wob, (int)(nw / 8));

  // fused QKV: B rows 0..2047 -> Q, 2048..4095 -> K, 4096..6143 -> V(T)
  gemm_3buf<0><<<dim3(3 * DM / 128, MROWS / 256), 512, 0, stream>>>(
      xb, wqb, Qb, Kb, Vtb);

  flash_attn<<<dim3(TSEQ / 128, BATCH * NH), 256, 0, stream>>>(Qb, Kb, Vtb, Ab);

  gemm_3buf<1><<<dim3(DM / 128, MROWS / 256), 512, 0, stream>>>(
      Ab, wob, out, nullptr, nullptr);
}

// Round 7
// 246.240 us; speedup vs baseline: 1.2209x; 1.0227x over previous
//
#include <hip/hip_runtime.h>

#define DM    2048
#define NH    16
#define HD    128
#define TSEQ  2048
#define BATCH 2
#define MROWS (BATCH * TSEQ)   // 4096

typedef __bf16 bf16_t;
typedef __bf16 bf16x8 __attribute__((ext_vector_type(8)));
typedef __bf16 bf16x4 __attribute__((ext_vector_type(4)));
typedef float  f32x4  __attribute__((ext_vector_type(4)));
typedef float  f32x16 __attribute__((ext_vector_type(16)));
typedef unsigned short u16x8 __attribute__((ext_vector_type(8)));
typedef unsigned int   u32;

static __device__ __forceinline__ unsigned short f2bf_bits(float f) {
  unsigned u = __builtin_bit_cast(unsigned, f);
  u += 0x7fffu + ((u >> 16) & 1u);            // round-to-nearest-even
  return (unsigned short)(u >> 16);
}
static __device__ __forceinline__ bf16_t f2bf(float f) {
  unsigned short h = f2bf_bits(f);
  return __builtin_bit_cast(bf16_t, h);
}

static __device__ __forceinline__ void gll16(const void* g, void* lds) {
  __builtin_amdgcn_global_load_lds(
      (const __attribute__((address_space(1))) unsigned int*)g,
      (__attribute__((address_space(3))) unsigned int*)lds, 16, 0, 0);
}

static __device__ __forceinline__ float fast_exp2(float x) {
#if __has_builtin(__builtin_amdgcn_exp2f)
  return __builtin_amdgcn_exp2f(x);
#else
  return exp2f(x);
#endif
}
static __device__ __forceinline__ float fast_rcp(float x) {
#if __has_builtin(__builtin_amdgcn_rcpf)
  return __builtin_amdgcn_rcpf(x);
#else
  return 1.0f / x;
#endif
}

// v_cvt_pk_bf16_f32: dst.lo16 = bf16(a), dst.hi16 = bf16(b)
static __device__ __forceinline__ u32 cvtpk(float a, float b) {
  u32 d;
  asm("v_cvt_pk_bf16_f32 %0, %1, %2" : "=v"(d) : "v"(a), "v"(b));
  return d;
}
// v_permlane32_swap_b32 a, b: a.hi32lanes <-> b.lo32lanes
static __device__ __forceinline__ void pl32swap(u32& a, u32& b) {
  asm volatile("v_permlane32_swap_b32 %0, %1" : "+v"(a), "+v"(b));
}

// ---------------- fp32 -> bf16 convert (vectorized, G13) ----------------
__global__ void cvt_bf16(const float* __restrict__ s, bf16_t* __restrict__ d, int n8) {
  int i = blockIdx.x * blockDim.x + threadIdx.x;
  if (i >= n8) return;
  const float4* sp = reinterpret_cast<const float4*>(s);
  float4 a = sp[2 * i], b = sp[2 * i + 1];
  u16x8 o;
  o[0] = f2bf_bits(a.x); o[1] = f2bf_bits(a.y); o[2] = f2bf_bits(a.z); o[3] = f2bf_bits(a.w);
  o[4] = f2bf_bits(b.x); o[5] = f2bf_bits(b.y); o[6] = f2bf_bits(b.z); o[7] = f2bf_bits(b.w);
  reinterpret_cast<u16x8*>(d)[i] = o;
}

// ---------------- 3-buffer counted-vmcnt GEMM: C[M,N] = A[M,K] * B[N,K]^T ------
// BM=256, BN=128, BK=64, 512 thr = 8 waves (4M x 2N), per-wave 64x64.
// 3 LDS buffers: compute tile j from buf j%3, stage tile j+2 into buf (j+2)%3.
// vmcnt(6) once per K-tile; NEVER vmcnt(0) in the main loop. Raw s_barrier.
// XOR swizzle u^=(row&7) on 128B rows via pre-swizzled global src (both sides).
template <int OUTM>
__global__ __launch_bounds__(512, 1) void gemm_3buf(
    const bf16_t* __restrict__ A, const bf16_t* __restrict__ B,
    void* __restrict__ Cq, void* __restrict__ Ck, void* __restrict__ Cv) {
  __shared__ bf16_t Asm[3][256 * 64];   // 96 KB
  __shared__ bf16_t Bsm[3][128 * 64];   // 48 KB
  const int tid = threadIdx.x;
  const int l = tid & 63, w = tid >> 6;
  const int wm = w >> 1, wn = w & 1;
  const int m0 = blockIdx.y * 256, n0 = blockIdx.x * 128;
  const int NT = DM / 64;   // 32

  auto SA = [&](int t, int buf, int s) {          // s = 0..3 (A: 256 rows)
    const int rowbase = s * 64 + w * 8;           // wave-uniform
    const int row = rowbase + (l >> 3);
    const int ug = (l & 7) ^ (row & 7);
    const int tc = (t < NT) ? t : 0;              // dummy clamp (keeps vmcnt uniform)
    gll16(A + (size_t)(m0 + row) * DM + tc * 64 + ug * 8,
          (char*)Asm[buf] + rowbase * 128);
  };
  auto SB = [&](int t, int buf, int s) {          // s = 0..1 (B: 128 rows)
    const int rowbase = s * 64 + w * 8;
    const int row = rowbase + (l >> 3);
    const int ug = (l & 7) ^ (row & 7);
    const int tc = (t < NT) ? t : 0;
    gll16(B + (size_t)(n0 + row) * DM + tc * 64 + ug * 8,
          (char*)Bsm[buf] + rowbase * 128);
  };

  f32x4 acc[4][4] = {};

  // Prologue: stage tiles 0 and 1 (6 loads each).
#pragma unroll
  for (int s = 0; s < 4; ++s) SA(0, 0, s);
  SB(0, 0, 0); SB(0, 0, 1);
#pragma unroll
  for (int s = 0; s < 4; ++s) SA(1, 1, s);
  SB(1, 1, 0); SB(1, 1, 1);
  asm volatile("s_waitcnt vmcnt(6)" ::: "memory");   // tile 0 complete
  __builtin_amdgcn_s_barrier();
  __builtin_amdgcn_sched_barrier(0);

  for (int j = 0; j < NT; ++j) {
    const int bj = j % 3, bs = (j + 2) % 3;
    const char* Ab_ = (const char*)Asm[bj];
    const char* Bb_ = (const char*)Bsm[bj];
    bf16x8 af[4][2], bfr[4][2];

    // ---- phase A: all A-frags + B-frags ni 0..1; stage A s0..s2 of tile j+2 ----
#pragma unroll
    for (int mi = 0; mi < 4; ++mi)
#pragma unroll
      for (int kh = 0; kh < 2; ++kh) {
        const int row = wm * 64 + mi * 16 + (l & 15);
        const int u = (kh * 4 + (l >> 4)) ^ (row & 7);
        af[mi][kh] = *reinterpret_cast<const bf16x8*>(Ab_ + row * 128 + u * 16);
      }
#pragma unroll
    for (int ni = 0; ni < 2; ++ni)
#pragma unroll
      for (int kh = 0; kh < 2; ++kh) {
        const int row = wn * 64 + ni * 16 + (l & 15);
        const int u = (kh * 4 + (l >> 4)) ^ (row & 7);
        bfr[ni][kh] = *reinterpret_cast<const bf16x8*>(Bb_ + row * 128 + u * 16);
      }
    SA(j + 2, bs, 0); SA(j + 2, bs, 1); SA(j + 2, bs, 2);
    __builtin_amdgcn_s_barrier();
    asm volatile("s_waitcnt lgkmcnt(0)" ::: "memory");
    __builtin_amdgcn_sched_barrier(0);
    __builtin_amdgcn_s_setprio(1);
#pragma unroll
    for (int mi = 0; mi < 4; ++mi)
#pragma unroll
      for (int ni = 0; ni < 2; ++ni)
#pragma unroll
        for (int kh = 0; kh < 2; ++kh)
          acc[mi][ni] = __builtin_amdgcn_mfma_f32_16x16x32_bf16(
              af[mi][kh], bfr[ni][kh], acc[mi][ni], 0, 0, 0);
    __builtin_amdgcn_s_setprio(0);
    __builtin_amdgcn_s_barrier();
    __builtin_amdgcn_sched_barrier(0);

    // ---- phase B: B-frags ni 2..3; stage A s3 + B s0..s1 of tile j+2 ----
#pragma unroll
    for (int ni = 2; ni < 4; ++ni)
#pragma unroll
      for (int kh = 0; kh < 2; ++kh) {
        const int row = wn * 64 + ni * 16 + (l & 15);
        const int u = (kh * 4 + (l >> 4)) ^ (row & 7);
        bfr[ni][kh] = *reinterpret_cast<const bf16x8*>(Bb_ + row * 128 + u * 16);
      }
    SA(j + 2, bs, 3); SB(j + 2, bs, 0); SB(j + 2, bs, 1);
    __builtin_amdgcn_s_barrier();
    asm volatile("s_waitcnt lgkmcnt(0)" ::: "memory");
    __builtin_amdgcn_sched_barrier(0);
    __builtin_amdgcn_s_setprio(1);
#pragma unroll
    for (int mi = 0; mi < 4; ++mi)
#pragma unroll
      for (int ni = 2; ni < 4; ++ni)
#pragma unroll
        for (int kh = 0; kh < 2; ++kh)
          acc[mi][ni] = __builtin_amdgcn_mfma_f32_16x16x32_bf16(
              af[mi][kh], bfr[ni][kh], acc[mi][ni], 0, 0, 0);
    __builtin_amdgcn_s_setprio(0);
    // counted: only tile j+2's 6 loads may remain in flight -> tile j+1 ready
    asm volatile("s_waitcnt vmcnt(6)" ::: "memory");
    __builtin_amdgcn_s_barrier();
    __builtin_amdgcn_sched_barrier(0);
  }

  // ---- epilogue ----
  if constexpr (OUTM == 0) {
    const int proj = n0 >> 11;          // 0=Q, 1=K, 2=V (uniform per WG)
    const int nc0 = n0 & (DM - 1);
    if (proj < 2) {
      bf16_t* C = (bf16_t*)(proj == 0 ? Cq : Ck);
#pragma unroll
      for (int mi = 0; mi < 4; ++mi) {
        const int row = m0 + wm * 64 + mi * 16 + ((l >> 4) << 2);
#pragma unroll
        for (int ni = 0; ni < 4; ++ni) {
          const int col = nc0 + wn * 64 + ni * 16 + (l & 15);
#pragma unroll
          for (int r = 0; r < 4; ++r)
            C[(size_t)(row + r) * DM + col] = f2bf(acc[mi][ni][r]);
        }
      }
    } else {
      bf16_t* VT = (bf16_t*)Cv;
#pragma unroll
      for (int mi = 0; mi < 4; ++mi) {
        const int row = m0 + wm * 64 + mi * 16 + ((l >> 4) << 2);
        const int bb = row >> 11, tt = row & (TSEQ - 1);
#pragma unroll
        for (int ni = 0; ni < 4; ++ni) {
          const int col = nc0 + wn * 64 + ni * 16 + (l & 15);
          const int hh = col >> 7, dd = col & (HD - 1);
          bf16x4 pk;
#pragma unroll
          for (int r = 0; r < 4; ++r) pk[r] = f2bf(acc[mi][ni][r]);
          *reinterpret_cast<bf16x4*>(VT + (((size_t)bb * NH + hh) * HD + dd) * TSEQ + tt) = pk;
        }
      }
    }
  } else {
    float* C = (float*)Cq;
#pragma unroll
    for (int mi = 0; mi < 4; ++mi) {
      const int row = m0 + wm * 64 + mi * 16 + ((l >> 4) << 2);
#pragma unroll
      for (int ni = 0; ni < 4; ++ni) {
        const int col = n0 + wn * 64 + ni * 16 + (l & 15);
#pragma unroll
        for (int r = 0; r < 4; ++r)
          C[(size_t)(row + r) * DM + col] = acc[mi][ni][r];
      }
    }
  }
}

// ---------------- causal flash attention v5: paired q-tiles for balance ----------
// grid: (T/256, B*H) = (8, 32) = 256 identical-work blocks (1 full CU round).
// Block i runs q-tile i (2i+2 k-tiles), then q-tile 15-i (32-2i): 34 tiles each.
// Per q-tile: 4 waves x 32 q-rows, swapped-QK 32x32, in-register softmax.
__global__ __launch_bounds__(256, 2) void flash_attn(
    const bf16_t* __restrict__ Q, const bf16_t* __restrict__ Kx,
    const bf16_t* __restrict__ VT, bf16_t* __restrict__ O) {
  __shared__ bf16_t Ks[2][64 * 128];   // [kv][d], 256B rows, XOR-swizzled content
  __shared__ bf16_t Vs[2][128 * 64];   // [d][kv], 128B rows, XOR-swizzled content
  __shared__ float  Ms[4][32];         // per-wave scl/lrow redistribute buffer

  const int tid = threadIdx.x;
  const int l = tid & 63, w = tid >> 6;
  const int hi = l >> 5, ln31 = l & 31;
  const int bh = blockIdx.y;
  const int b = bh >> 4, h = bh & 15;
  const size_t base   = ((size_t)b * TSEQ) * DM + (size_t)h * HD;   // Q/K/O
  const size_t vtbase = ((size_t)b * NH + h) * HD * (size_t)TSEQ;   // V^T

  auto run_qtile = [&](int qb) {
    const int wq0 = qb * 128 + w * 32;
    const int nt = 2 * qb + 2;

    // Q as B-operand: lane holds col q = ln31, k(d) = m*16 + hi*8 + j
    bf16x8 qf[8];
    {
      const bf16_t* qp = Q + base + (size_t)(wq0 + ln31) * DM + hi * 8;
#pragma unroll
      for (int m = 0; m < 8; ++m)
        qf[m] = *reinterpret_cast<const bf16x8*>(qp + m * 16);
    }

    f32x16 acc[4] = {};   // O: row q=crow(r,hi), col d = n*32 + ln31
    float mrow = -1e30f, lrow = 0.f;
    const float cc = 0.12752775f;  // (1/sqrt(128)) * log2(e)

    auto STAGE = [&](int t, int buf) {
#pragma unroll
      for (int c = 0; c < 4; ++c) {
        const int chunk = w * 4 + c;                   // 0..15
        const int krow = chunk * 4 + (l >> 4);
        const int u = l & 15;
        const int ug = (u & 8) | ((u ^ krow) & 7);
        gll16(Kx + base + (size_t)(t * 64 + krow) * DM + ug * 8,
              (char*)Ks[buf] + chunk * 1024);
      }
#pragma unroll
      for (int c = 0; c < 4; ++c) {
        const int ci = w * 4 + c;                      // 0..15
        const int d = ci * 8 + (l >> 3);
        const int ug = (l & 7) ^ (l >> 3);
        gll16(VT + vtbase + (size_t)d * TSEQ + t * 64 + ug * 8,
              (char*)Vs[buf] + ci * 1024);
      }
    };

    STAGE(0, 0);
    __syncthreads();
    int cur = 0;

    for (int t = 0; t < nt; ++t) {
      if (t + 1 < nt) STAGE(t + 1, cur ^ 1);

      const bool active = (t * 64 <= wq0 + 31);
      if (active) {
        // ---- S^T = K Q^T : 2 kv-subtiles of 32 ----
        f32x16 s[2] = {};
        const char* Kb_ = (const char*)Ks[cur];
#pragma unroll
        for (int si = 0; si < 2; ++si) {
          const int kvr = si * 32 + ln31;
#pragma unroll
          for (int m = 0; m < 8; ++m) {
            const int u = 2 * m + hi;
            const int uswz = (u & 8) | ((u ^ kvr) & 7);
            const bf16x8 kf = *reinterpret_cast<const bf16x8*>(Kb_ + kvr * 256 + uswz * 16);
            s[si] = __builtin_amdgcn_mfma_f32_32x32x16_bf16(kf, qf[m], s[si], 0, 0, 0);
          }
        }

        // ---- scale + causal mask (per-lane: q = ln31, kv = crow(r,hi)) ----
        float sv[32];
        const int qg = wq0 + ln31;
#pragma unroll
        for (int si = 0; si < 2; ++si)
#pragma unroll
          for (int r = 0; r < 16; ++r)
            sv[si * 16 + r] = s[si][r] * cc;
        if (t * 64 + 63 > wq0) {
#pragma unroll
          for (int si = 0; si < 2; ++si)
#pragma unroll
            for (int r = 0; r < 16; ++r) {
              const int kvg = t * 64 + si * 32 + (r & 3) + 8 * (r >> 2) + 4 * hi;
              if (kvg > qg) sv[si * 16 + r] = -3.0e38f;
            }
        }

        // ---- in-register row max + cross-half combine ----
        float mt = sv[0];
#pragma unroll
        for (int r = 1; r < 32; ++r) mt = fmaxf(mt, sv[r]);
        mt = fmaxf(mt, __shfl_xor(mt, 32, 64));

        // T13 defer-max
        if (__any(mt > mrow + 8.0f)) {
          const float mn = fmaxf(mrow, mt);
          const float scl = fast_exp2(mrow - mn);
          mrow = mn;
          lrow *= scl;
          if (hi == 0) Ms[w][ln31] = scl;
          float sclg[16];
#pragma unroll
          for (int r = 0; r < 16; ++r)
            sclg[r] = Ms[w][(r & 3) + 8 * (r >> 2) + 4 * hi];
#pragma unroll
          for (int n = 0; n < 4; ++n)
#pragma unroll
            for (int r = 0; r < 16; ++r)
              acc[n][r] *= sclg[r];
        }

        // ---- P = exp2(S - m), row sum ----
        float rs = 0.f;
#pragma unroll
        for (int r = 0; r < 32; ++r) {
          const float p = fast_exp2(sv[r] - mrow);
          sv[r] = p;
          rs += p;
        }
        rs += __shfl_xor(rs, 32, 64);
        lrow += rs;

        // ---- cvt_pk + permlane32_swap: build PV A-frags ----
        u32 frag[4][4];
#pragma unroll
        for (int si = 0; si < 2; ++si) {
#pragma unroll
          for (int half = 0; half < 2; ++half) {
            const float* p = &sv[si * 16 + half * 8];
            u32 a1 = cvtpk(p[0], p[1]);
            u32 b1 = cvtpk(p[4], p[5]);
            pl32swap(a1, b1);
            u32 a2 = cvtpk(p[2], p[3]);
            u32 b2 = cvtpk(p[6], p[7]);
            pl32swap(a2, b2);
            frag[si * 2 + half][0] = a1;
            frag[si * 2 + half][1] = a2;
            frag[si * 2 + half][2] = b1;
            frag[si * 2 + half][3] = b2;
          }
        }

        // ---- O += P V : 4 kv-slots x 4 d-tiles ----
        const char* Vb_ = (const char*)Vs[cur];
#pragma unroll
        for (int ks = 0; ks < 4; ++ks) {
          const bf16x8 pf = __builtin_bit_cast(bf16x8, *reinterpret_cast<u32(*)[4]>(frag[ks]));
#pragma unroll
          for (int n = 0; n < 4; ++n) {
            const int d = n * 32 + ln31;
            const int u = ks * 2 + hi;
            const int uswz = u ^ (d & 7);
            const bf16x8 vf = *reinterpret_cast<const bf16x8*>(Vb_ + d * 128 + uswz * 16);
            acc[n] = __builtin_amdgcn_mfma_f32_32x32x16_bf16(pf, vf, acc[n], 0, 0, 0);
          }
        }
      }
      __syncthreads();
      cur ^= 1;
    }

    // ---- epilogue: redistribute lrow, normalize, store ----
    if (hi == 0) Ms[w][ln31] = lrow;
    __syncthreads();
    float rl[16];
#pragma unroll
    for (int r = 0; r < 16; ++r)
      rl[r] = fast_rcp(Ms[w][(r & 3) + 8 * (r >> 2) + 4 * hi]);
#pragma unroll
    for (int r = 0; r < 16; ++r) {
      const int q = wq0 + (r & 3) + 8 * (r >> 2) + 4 * hi;
      bf16_t* op = O + base + (size_t)q * DM + ln31;
#pragma unroll
      for (int n = 0; n < 4; ++n)
        op[n * 32] = f2bf(acc[n][r] * rl[r]);
    }
    __syncthreads();   // Ms/LDS safe for next q-tile
  };

  const int i = blockIdx.x;               // 0..7
  run_qtile(i);                           // short leg: 2i+2 k-tiles
  run_qtile((int)(TSEQ / 128) - 1 - i);   // long leg: 32-2i k-tiles (total 34)
}

// ---------------- launch ----------------
extern "C" void kernel_launch(void* const* d_in, const int* in_sizes, int n_in,
                              void* d_out, int out_size, void* d_ws, size_t ws_size,
                              hipStream_t stream) {
  (void)in_sizes; (void)n_in; (void)out_size; (void)ws_size;
  const float* x  = (const float*)d_in[0];
  const float* wq = (const float*)d_in[1];
  const float* wk = (const float*)d_in[2];
  const float* wv = (const float*)d_in[3];
  const float* wo = (const float*)d_in[4];
  float* out = (float*)d_out;

  const size_t nx = (size_t)MROWS * DM;  // 8388608
  const size_t nw = (size_t)DM * DM;     // 4194304
  bf16_t* xb  = (bf16_t*)d_ws;
  bf16_t* wqb = xb + nx;                 // wq/wk/wv contiguous -> fused B [6144][2048]
  bf16_t* wkb = wqb + nw;
  bf16_t* wvb = wkb + nw;
  bf16_t* wob = wvb + nw;
  bf16_t* Qb  = wob + nw;
  bf16_t* Kb  = Qb + nx;
  bf16_t* Vtb = Kb + nx;   // V^T [B][H][d][t]
  bf16_t* Ab  = Vtb + nx;

  cvt_bf16<<<(int)(nx / 8 / 256), 256, 0, stream>>>(x, xb, (int)(nx / 8));
  cvt_bf16<<<(int)(nw / 8 / 256), 256, 0, stream>>>(wq, wqb, (int)(nw / 8));
  cvt_bf16<<<(int)(nw / 8 / 256), 256, 0, stream>>>(wk, wkb, (int)(nw / 8));
  cvt_bf16<<<(int)(nw / 8 / 256), 256, 0, stream>>>(wv, wvb, (int)(nw / 8));
  cvt_bf16<<<(int)(nw / 8 / 256), 256, 0, stream>>>(wo, wob, (int)(nw / 8));

  // fused QKV: B rows 0..2047 -> Q, 2048..4095 -> K, 4096..6143 -> V(T)
  gemm_3buf<0><<<dim3(3 * DM / 128, MROWS / 256), 512, 0, stream>>>(
      xb, wqb, Qb, Kb, Vtb);

  flash_attn<<<dim3(TSEQ / 256, BATCH * NH), 256, 0, stream>>>(Qb, Kb, Vtb, Ab);

  gemm_3buf<1><<<dim3(DM / 128, MROWS / 256), 512, 0, stream>>>(
      Ab, wob, out, nullptr, nullptr);
}